// Round 16
// baseline (110.084 us; speedup 1.0000x reference)
//
#include <hip/hip_runtime.h>
#include <cstdint>
#include <cfloat>
#include <cmath>

#define NPTS 65536
#define NB 16
#define NS 20
#define KK 10
#define FPB 16      // FPS blocks per batch
#define NSm1 (NS - 1)

struct InitIdx { int idx[NB]; };

static __device__ __forceinline__ unsigned long long
agent_ld(const unsigned long long* p) {
    return __hip_atomic_load(p, __ATOMIC_RELAXED, __HIP_MEMORY_SCOPE_AGENT);
}

// ---------------- Kernel 1: distributed FPS (R12-verbatim, 46.5 us) ---------
__global__ __launch_bounds__(1024) void fps_kernel(const float* __restrict__ pcs,
                                                   int* __restrict__ seeds,
                                                   unsigned long long* __restrict__ fkey,
                                                   InitIdx init) {
    const int u   = blockIdx.x;
    const int xcd = u & 7;              // XCD heuristic (perf-only)
    const int k   = u >> 3;             // 0..31
    const int b   = 2 * xcd + (k >> 4); // batch
    const int j   = k & 15;             // block-in-batch
    const int t   = threadIdx.x;
    const int lane = t & 63;
    const int w    = t >> 6;
    const float* __restrict__ base = pcs + (size_t)b * NPTS * 3;
    const int pbase = j * 4096 + t * 4; // 4 contiguous points per thread

    const float4* q4 = reinterpret_cast<const float4*>(base + (size_t)pbase * 3);
    float4 A = q4[0], Bv = q4[1], Cv = q4[2];
    float x[4] = { A.x, A.w, Bv.z, Cv.y };
    float y[4] = { A.y, Bv.x, Bv.w, Cv.z };
    float z[4] = { A.z, Bv.y, Cv.x, Cv.w };
    float dm[4] = { 1e10f, 1e10f, 1e10f, 1e10f };

    __shared__ float s_val[16];
    __shared__ int   s_idx[16];
    __shared__ int   s_far;

    int far = init.idx[b];

    for (int s = 0; s < NS; ++s) {
        if (j == 0 && t == 0) seeds[b * NS + s] = far;   // seed s BEFORE update
        if (s == NSm1) break;                            // last update unused

        const float* c = base + (size_t)far * 3;         // uniform, cached
        const float cx = c[0], cy = c[1], cz = c[2];

        float bestv = -1.0f;
        int   besti = 0;
#pragma unroll
        for (int q = 0; q < 4; ++q) {
            // match XLA: rounded sub/mul, sequential adds, NO fma contraction
            float dx = __fsub_rn(x[q], cx);
            float dy = __fsub_rn(y[q], cy);
            float dz = __fsub_rn(z[q], cz);
            float d  = __fadd_rn(__fadd_rn(__fmul_rn(dx, dx), __fmul_rn(dy, dy)),
                                 __fmul_rn(dz, dz));
            dm[q] = fminf(dm[q], d);
            // q ascending = index ascending; strict > keeps first occurrence
            if (dm[q] > bestv) { bestv = dm[q]; besti = pbase + q; }
        }
#pragma unroll
        for (int off = 32; off >= 1; off >>= 1) {
            float ov = __shfl_down(bestv, off);
            int   oi = __shfl_down(besti, off);
            if (ov > bestv || (ov == bestv && oi < besti)) { bestv = ov; besti = oi; }
        }
        if (lane == 0) { s_val[w] = bestv; s_idx[w] = besti; }
        __syncthreads();                                 // B1

        if (w == 0) {
            // parallel 16-lane block reduce -> packed key -> publish
            unsigned long long kv = 0ULL;
            if (lane < 16) {
                kv = ((unsigned long long)__float_as_uint(s_val[lane]) << 32) |
                     (unsigned long long)(0xFFFFFFFFu - (unsigned int)s_idx[lane]);
            }
#pragma unroll
            for (int off = 8; off >= 1; off >>= 1) {
                unsigned int lo = (unsigned int)kv, hi = (unsigned int)(kv >> 32);
                unsigned int olo = (unsigned int)__shfl_xor((int)lo, off);
                unsigned int ohi = (unsigned int)__shfl_xor((int)hi, off);
                unsigned long long o = ((unsigned long long)ohi << 32) | olo;
                if (o > kv) kv = o;
            }
            unsigned long long* fp = fkey + (size_t)(b * NS + s) * FPB;
            if (lane == 0)
                __hip_atomic_store(&fp[j], kv, __ATOMIC_RELAXED,
                                   __HIP_MEMORY_SCOPE_AGENT);

            // 3-deep pipelined poll of the 16 slots (lane l watches slot l&15)
            const unsigned long long* sl = fp + (lane & 15);
            unsigned long long p0 = agent_ld(sl);
            unsigned long long p1 = agent_ld(sl);
            unsigned long long p2 = agent_ld(sl);
            unsigned long long v;
            for (;;) {
                if (!__any(p0 == 0ULL)) { v = p0; break; }
                p0 = agent_ld(sl);
                if (!__any(p1 == 0ULL)) { v = p1; break; }
                p1 = agent_ld(sl);
                if (!__any(p2 == 0ULL)) { v = p2; break; }
                p2 = agent_ld(sl);
            }
#pragma unroll
            for (int off = 32; off >= 1; off >>= 1) {
                unsigned int lo = (unsigned int)v, hi = (unsigned int)(v >> 32);
                unsigned int olo = (unsigned int)__shfl_xor((int)lo, off);
                unsigned int ohi = (unsigned int)__shfl_xor((int)hi, off);
                unsigned long long o = ((unsigned long long)ohi << 32) | olo;
                if (o > v) v = o;
            }
            if (lane == 0)
                s_far = (int)(0xFFFFFFFFu - (unsigned int)(v & 0xFFFFFFFFull));
        }
        __syncthreads();                                 // B2
        far = s_far;
    }
}

// ---- branchless sorted insert into an 11-list (independent med3 ops) -------
#define INS11(L, SQ)                                                     \
    {                                                                    \
        _Pragma("unroll")                                                \
        for (int jj = 10; jj >= 1; --jj)                                 \
            L[jj] = __builtin_amdgcn_fmed3f(L[jj - 1], L[jj], (SQ));     \
        L[0] = fminf(L[0], (SQ));                                        \
    }

// ---------------- Kernel 2: knn scan — 4 independent lists + prefetch -------
// R13 even grid: 1280 blocks x 256 thr = 5 blocks/CU (20 waves/CU).
// Latency fixes vs R13 (scan was ~25us at ~28% VALU busy):
//  (1) point-slot q -> its OWN list lq: the per-point sq->insert dependency
//      chain is split 4 ways (4x ILP); lists merge exactly in the wave-pop
//      by taking min over the 4 heads.
//  (2) next iteration's 3 float4s prefetched before processing the current
//      ones, hiding L2 latency under the ~76-instr body.
__global__ __launch_bounds__(256, 5) void knn_scan(const float* __restrict__ pcs,
                                                   const int* __restrict__ seeds,
                                                   float* __restrict__ part) {
    const int u   = blockIdx.x;        // 0..1279
    const int xcd = u & 7;
    const int k   = u >> 3;            // 0..159
    const int b   = 2 * xcd + (k / 80);
    const int rem = k % 80;
    const int s   = rem >> 2;          // 0..19
    const int c   = rem & 3;           // chunk 0..3
    const int t = threadIdx.x;         // 0..255
    const int lane = t & 63;
    const int w = t >> 6;              // wave 0..3
    const float* __restrict__ base = pcs + (size_t)b * NPTS * 3;
    const int sidx = seeds[b * NS + s];
    const float cx = base[(size_t)sidx * 3 + 0];
    const float cy = base[(size_t)sidx * 3 + 1];
    const float cz = base[(size_t)sidx * 3 + 2];

    float l0[11], l1[11], l2[11], l3[11];
#pragma unroll
    for (int jj = 0; jj < 11; ++jj) { l0[jj] = FLT_MAX; l1[jj] = FLT_MAX;
                                      l2[jj] = FLT_MAX; l3[jj] = FLT_MAX; }

    // prefetch iteration 0
    const float4* qp = reinterpret_cast<const float4*>(
        base + (size_t)(c * 16384 + t * 4) * 3);
    float4 A = qp[0], Bv = qp[1], Cv = qp[2];

    for (int i = 0; i < 16; ++i) {
        float4 nA, nB, nC;
        if (i < 15) {
            const float4* np = reinterpret_cast<const float4*>(
                base + (size_t)(c * 16384 + (i + 1) * 1024 + t * 4) * 3);
            nA = np[0]; nB = np[1]; nC = np[2];
        }
        const float px0 = A.x,  py0 = A.y,  pz0 = A.z;
        const float px1 = A.w,  py1 = Bv.x, pz1 = Bv.y;
        const float px2 = Bv.z, py2 = Bv.w, pz2 = Cv.x;
        const float px3 = Cv.y, py3 = Cv.z, pz3 = Cv.w;

        {   float dx = __fsub_rn(px0, cx), dy = __fsub_rn(py0, cy), dz = __fsub_rn(pz0, cz);
            float sq = __fadd_rn(__fadd_rn(__fmul_rn(dx, dx), __fmul_rn(dy, dy)), __fmul_rn(dz, dz));
            INS11(l0, sq); }
        {   float dx = __fsub_rn(px1, cx), dy = __fsub_rn(py1, cy), dz = __fsub_rn(pz1, cz);
            float sq = __fadd_rn(__fadd_rn(__fmul_rn(dx, dx), __fmul_rn(dy, dy)), __fmul_rn(dz, dz));
            INS11(l1, sq); }
        {   float dx = __fsub_rn(px2, cx), dy = __fsub_rn(py2, cy), dz = __fsub_rn(pz2, cz);
            float sq = __fadd_rn(__fadd_rn(__fmul_rn(dx, dx), __fmul_rn(dy, dy)), __fmul_rn(dz, dz));
            INS11(l2, sq); }
        {   float dx = __fsub_rn(px3, cx), dy = __fsub_rn(py3, cy), dz = __fsub_rn(pz3, cz);
            float sq = __fadd_rn(__fadd_rn(__fmul_rn(dx, dx), __fmul_rn(dy, dy)), __fmul_rn(dz, dz));
            INS11(l3, sq); }

        A = nA; Bv = nB; Cv = nC;
    }

    // wave-level top-11: 11 rounds of (wave-min over 4 heads, pop one copy).
    // Exact: every wave-top-11 element is at the head of its lane's list when
    // selected; ties pop exactly one copy (single lane, single list).
    float* pr = part + ((size_t)((b * NS + s) * 4 + c) * 4 + w) * 11;
    for (int r = 0; r < 11; ++r) {
        float h = fminf(fminf(l0[0], l1[0]), fminf(l2[0], l3[0]));
        float v = h;
#pragma unroll
        for (int off = 32; off >= 1; off >>= 1) v = fminf(v, __shfl_xor(v, off));
        unsigned long long m = __ballot(h == v);
        if (lane == (int)__ffsll(m) - 1) {
            if (l0[0] == v) {
#pragma unroll
                for (int jj = 0; jj < 10; ++jj) l0[jj] = l0[jj + 1];
                l0[10] = FLT_MAX;
            } else if (l1[0] == v) {
#pragma unroll
                for (int jj = 0; jj < 10; ++jj) l1[jj] = l1[jj + 1];
                l1[10] = FLT_MAX;
            } else if (l2[0] == v) {
#pragma unroll
                for (int jj = 0; jj < 10; ++jj) l2[jj] = l2[jj + 1];
                l2[10] = FLT_MAX;
            } else {
#pragma unroll
                for (int jj = 0; jj < 10; ++jj) l3[jj] = l3[jj + 1];
                l3[10] = FLT_MAX;
            }
        }
        if (lane == 0) pr[r] = v;
    }
}

// ---------------- Kernel 3: merge 176 -> top-11 + repulsion epilogue --------
// 320 blocks x 1 wave; R13-verbatim final-merge reading global part.
__global__ __launch_bounds__(64) void knn_merge(const float* __restrict__ part,
                                               float* __restrict__ out) {
    const int pair = blockIdx.x;       // 0..319
    const int lane = threadIdx.x;      // 0..63
    const float* flat = part + (size_t)pair * 176;
    float a0 = flat[lane];
    float a1 = flat[lane + 64];
    float a2 = (lane + 128 < 176) ? flat[lane + 128] : FLT_MAX;

    const float HH = (float)(0.01 * 0.01);   // JAX weak-typed scalar H*H
    float acc = 0.0f;
#pragma unroll
    for (int r = 0; r < 11; ++r) {
        float mymin = fminf(a0, fminf(a1, a2));
        float v = mymin;
#pragma unroll
        for (int off = 32; off >= 1; off >>= 1) v = fminf(v, __shfl_xor(v, off));
        unsigned long long m = __ballot(mymin == v);
        if (lane == (int)__ffsll(m) - 1) {
            if (a0 == v)      a0 = FLT_MAX;
            else if (a1 == v) a1 = FLT_MAX;
            else              a2 = FLT_MAX;
        }
        if (lane == 0 && r >= 1) {           // r==0 is self (dist 0)
            float sq = v;
            float d  = (sq == 0.0f) ? 0.0f : __fsqrt_rn(sq);
            float q2 = __fmul_rn(d, d);
            float wt = expf(__fdiv_rn(-q2, HH));
            acc = __fadd_rn(acc, -__fmul_rn(d, wt));
        }
    }
    if (lane == 0) atomicAdd(out, acc * 0.0625f);   // mean over B=16
}

// ---------------- Host: JAX threefry2x32 (partitionable mode) ---------------
static inline uint32_t rotl32(uint32_t x, uint32_t d) { return (x << d) | (x >> (32 - d)); }

static void tf2x32(uint32_t k0, uint32_t k1, uint32_t x0, uint32_t x1,
                   uint32_t& y0, uint32_t& y1) {
    const uint32_t ks[3] = { k0, k1, k0 ^ k1 ^ 0x1BD11BDAu };
    const uint32_t rotA[4] = { 13, 15, 26, 6 };
    const uint32_t rotB[4] = { 17, 29, 16, 24 };
    uint32_t v0 = x0 + ks[0], v1 = x1 + ks[1];
    for (int i = 0; i < 5; ++i) {
        const uint32_t* rot = (i % 2 == 0) ? rotA : rotB;
        for (int j = 0; j < 4; ++j) {
            v0 += v1;
            v1 = rotl32(v1, rot[j]);
            v1 ^= v0;
        }
        v0 += ks[(i + 1) % 3];
        v1 += ks[(i + 2) % 3] + (uint32_t)(i + 1);
    }
    y0 = v0; y1 = v1;
}

extern "C" void kernel_launch(void* const* d_in, const int* in_sizes, int n_in,
                              void* d_out, int out_size, void* d_ws, size_t ws_size,
                              hipStream_t stream) {
    const float* pcs = (const float*)d_in[0];
    float* out = (float*)d_out;

    // ws: [0,1280) seeds (int); [2048,43008) fps keys u64[16*20*16];
    //     [49152, 49152+320*176*4=274432) part f32
    int* seeds               = (int*)d_ws;
    unsigned long long* fkey = (unsigned long long*)((char*)d_ws + 2048);
    float* part              = (float*)((char*)d_ws + 49152);

    // jax.random.key(1) -> threefry key (0,1), partitionable mode:
    //   split foldlike: k2 = threefry((0,1),(0,1)) both words
    //   random_bits: counters (0,i), out = y0 ^ y1; randint span 2^16 -> mask
    uint32_t k2_0, k2_1;
    tf2x32(0u, 1u, 0u, 1u, k2_0, k2_1);
    InitIdx init;
    for (int i = 0; i < NB; ++i) {
        uint32_t y0, y1;
        tf2x32(k2_0, k2_1, 0u, (uint32_t)i, y0, y1);
        init.idx[i] = (int)((y0 ^ y1) & 0xFFFFu);
    }

    hipMemsetAsync(d_ws, 0, 43008, stream);   // seeds + fps keys
    hipMemsetAsync(d_out, 0, sizeof(float), stream);

    hipLaunchKernelGGL(fps_kernel, dim3(NB * FPB), dim3(1024), 0, stream,
                       pcs, seeds, fkey, init);
    hipLaunchKernelGGL(knn_scan, dim3(1280), dim3(256), 0, stream,
                       pcs, seeds, part);
    hipLaunchKernelGGL(knn_merge, dim3(320), dim3(64), 0, stream,
                       part, out);
}

// Round 17
// 86.346 us; speedup vs baseline: 1.2749x; 1.2749x over previous
//
#include <hip/hip_runtime.h>
#include <cstdint>
#include <cfloat>
#include <cmath>

#define NPTS 65536
#define NB 16
#define NS 20
#define KK 10
#define FPB 16      // FPS blocks per batch
#define NSm1 (NS - 1)
#define CANDCAP 2048

struct InitIdx { int idx[NB]; };

static __device__ __forceinline__ unsigned long long
agent_ld(const unsigned long long* p) {
    return __hip_atomic_load(p, __ATOMIC_RELAXED, __HIP_MEMORY_SCOPE_AGENT);
}

// ---------------- Kernel 1: distributed FPS (R12-verbatim, 46.5 us) ---------
__global__ __launch_bounds__(1024) void fps_kernel(const float* __restrict__ pcs,
                                                   int* __restrict__ seeds,
                                                   unsigned long long* __restrict__ fkey,
                                                   InitIdx init) {
    const int u   = blockIdx.x;
    const int xcd = u & 7;              // XCD heuristic (perf-only)
    const int k   = u >> 3;             // 0..31
    const int b   = 2 * xcd + (k >> 4); // batch
    const int j   = k & 15;             // block-in-batch
    const int t   = threadIdx.x;
    const int lane = t & 63;
    const int w    = t >> 6;
    const float* __restrict__ base = pcs + (size_t)b * NPTS * 3;
    const int pbase = j * 4096 + t * 4; // 4 contiguous points per thread

    const float4* q4 = reinterpret_cast<const float4*>(base + (size_t)pbase * 3);
    float4 A = q4[0], Bv = q4[1], Cv = q4[2];
    float x[4] = { A.x, A.w, Bv.z, Cv.y };
    float y[4] = { A.y, Bv.x, Bv.w, Cv.z };
    float z[4] = { A.z, Bv.y, Cv.x, Cv.w };
    float dm[4] = { 1e10f, 1e10f, 1e10f, 1e10f };

    __shared__ float s_val[16];
    __shared__ int   s_idx[16];
    __shared__ int   s_far;

    int far = init.idx[b];

    for (int s = 0; s < NS; ++s) {
        if (j == 0 && t == 0) seeds[b * NS + s] = far;   // seed s BEFORE update
        if (s == NSm1) break;                            // last update unused

        const float* c = base + (size_t)far * 3;         // uniform, cached
        const float cx = c[0], cy = c[1], cz = c[2];

        float bestv = -1.0f;
        int   besti = 0;
#pragma unroll
        for (int q = 0; q < 4; ++q) {
            // match XLA: rounded sub/mul, sequential adds, NO fma contraction
            float dx = __fsub_rn(x[q], cx);
            float dy = __fsub_rn(y[q], cy);
            float dz = __fsub_rn(z[q], cz);
            float d  = __fadd_rn(__fadd_rn(__fmul_rn(dx, dx), __fmul_rn(dy, dy)),
                                 __fmul_rn(dz, dz));
            dm[q] = fminf(dm[q], d);
            // q ascending = index ascending; strict > keeps first occurrence
            if (dm[q] > bestv) { bestv = dm[q]; besti = pbase + q; }
        }
#pragma unroll
        for (int off = 32; off >= 1; off >>= 1) {
            float ov = __shfl_down(bestv, off);
            int   oi = __shfl_down(besti, off);
            if (ov > bestv || (ov == bestv && oi < besti)) { bestv = ov; besti = oi; }
        }
        if (lane == 0) { s_val[w] = bestv; s_idx[w] = besti; }
        __syncthreads();                                 // B1

        if (w == 0) {
            // parallel 16-lane block reduce -> packed key -> publish
            unsigned long long kv = 0ULL;
            if (lane < 16) {
                kv = ((unsigned long long)__float_as_uint(s_val[lane]) << 32) |
                     (unsigned long long)(0xFFFFFFFFu - (unsigned int)s_idx[lane]);
            }
#pragma unroll
            for (int off = 8; off >= 1; off >>= 1) {
                unsigned int lo = (unsigned int)kv, hi = (unsigned int)(kv >> 32);
                unsigned int olo = (unsigned int)__shfl_xor((int)lo, off);
                unsigned int ohi = (unsigned int)__shfl_xor((int)hi, off);
                unsigned long long o = ((unsigned long long)ohi << 32) | olo;
                if (o > kv) kv = o;
            }
            unsigned long long* fp = fkey + (size_t)(b * NS + s) * FPB;
            if (lane == 0)
                __hip_atomic_store(&fp[j], kv, __ATOMIC_RELAXED,
                                   __HIP_MEMORY_SCOPE_AGENT);

            // 3-deep pipelined poll of the 16 slots (lane l watches slot l&15)
            const unsigned long long* sl = fp + (lane & 15);
            unsigned long long p0 = agent_ld(sl);
            unsigned long long p1 = agent_ld(sl);
            unsigned long long p2 = agent_ld(sl);
            unsigned long long v;
            for (;;) {
                if (!__any(p0 == 0ULL)) { v = p0; break; }
                p0 = agent_ld(sl);
                if (!__any(p1 == 0ULL)) { v = p1; break; }
                p1 = agent_ld(sl);
                if (!__any(p2 == 0ULL)) { v = p2; break; }
                p2 = agent_ld(sl);
            }
#pragma unroll
            for (int off = 32; off >= 1; off >>= 1) {
                unsigned int lo = (unsigned int)v, hi = (unsigned int)(v >> 32);
                unsigned int olo = (unsigned int)__shfl_xor((int)lo, off);
                unsigned int ohi = (unsigned int)__shfl_xor((int)hi, off);
                unsigned long long o = ((unsigned long long)ohi << 32) | olo;
                if (o > v) v = o;
            }
            if (lane == 0)
                s_far = (int)(0xFFFFFFFFu - (unsigned int)(v & 0xFFFFFFFFull));
        }
        __syncthreads();                                 // B2
        far = s_far;
    }
}

// ---- branchless sorted insert into an 11-list (independent med3 ops) -------
#define INS11(L, SQ)                                                     \
    {                                                                    \
        _Pragma("unroll")                                                \
        for (int jj = 10; jj >= 1; --jj)                                 \
            L[jj] = __builtin_amdgcn_fmed3f(L[jj - 1], L[jj], (SQ));     \
        L[0] = fminf(L[0], (SQ));                                        \
    }

// ---- wave-level top-11 pop of a sorted per-lane list into s_top[w] ---------
#define WAVEPOP11(L, DEST)                                               \
    for (int r = 0; r < 11; ++r) {                                       \
        float v = L[0];                                                  \
        _Pragma("unroll")                                                \
        for (int off = 32; off >= 1; off >>= 1)                          \
            v = fminf(v, __shfl_xor(v, off));                            \
        unsigned long long m = __ballot(L[0] == v);                      \
        if (lane == (int)__ffsll(m) - 1) {                               \
            _Pragma("unroll")                                            \
            for (int jj = 0; jj < 10; ++jj) L[jj] = L[jj + 1];           \
            L[10] = FLT_MAX;                                             \
        }                                                                \
        if (lane == 0) (DEST)[r] = v;                                    \
    }

// ---------------- Kernel 2: knn scan via threshold filter -------------------
// Block = (pair, chunk of 16384), 1280 blocks x 256 thr.
// Phase 1: exact top-11 of a 1024-pt subset -> T (upper bound on chunk's
//   11th smallest, since subset ⊂ chunk).
// Phase 2 (hot, ~10 ops/pt, NO list state, NO serial chain): collect all
//   sq <= T into an LDS buffer (E[hits]≈176, cap 2048 = +25σ for the fixed
//   uniform input). <= keeps ties -> candidate multiset ⊇ true top-11.
// Phase 3: exact top-11 of candidates via med3 + wave-pop + 44-merge.
// Small state -> no spill at any occupancy (R13-R16 lesson: register top-11
// lists force the VGPR/occupancy tradeoff; the filter dodges it).
__global__ __launch_bounds__(256, 4) void knn_scan(const float* __restrict__ pcs,
                                                   const int* __restrict__ seeds,
                                                   float* __restrict__ part) {
    const int u   = blockIdx.x;        // 0..1279
    const int xcd = u & 7;
    const int k   = u >> 3;            // 0..159
    const int b   = 2 * xcd + (k / 80);
    const int rem = k % 80;
    const int s   = rem >> 2;          // 0..19
    const int c   = rem & 3;           // chunk 0..3
    const int t = threadIdx.x;         // 0..255
    const int lane = t & 63;
    const int w = t >> 6;              // wave 0..3
    const float* __restrict__ base = pcs + (size_t)b * NPTS * 3;
    const int sidx = seeds[b * NS + s];
    const float cx = base[(size_t)sidx * 3 + 0];
    const float cy = base[(size_t)sidx * 3 + 1];
    const float cz = base[(size_t)sidx * 3 + 2];

    __shared__ float s_top[4][11];
    __shared__ float s_T;
    __shared__ int   s_cnt;
    __shared__ float cand[CANDCAP];

    if (t == 0) s_cnt = 0;

    // ---- phase 1: subset = first 1024 pts of chunk (4/thread) -> T ---------
    float lst[11];
#pragma unroll
    for (int jj = 0; jj < 11; ++jj) lst[jj] = FLT_MAX;
    {
        const int pb = c * 16384 + t * 4;
        const float4* q4 = reinterpret_cast<const float4*>(base + (size_t)pb * 3);
        float4 A = q4[0], Bv = q4[1], Cv = q4[2];
        float px[4] = { A.x, A.w, Bv.z, Cv.y };
        float py[4] = { A.y, Bv.x, Bv.w, Cv.z };
        float pz[4] = { A.z, Bv.y, Cv.x, Cv.w };
#pragma unroll
        for (int q = 0; q < 4; ++q) {
            float dx = __fsub_rn(px[q], cx);
            float dy = __fsub_rn(py[q], cy);
            float dz = __fsub_rn(pz[q], cz);
            float sq = __fadd_rn(__fadd_rn(__fmul_rn(dx, dx), __fmul_rn(dy, dy)),
                                 __fmul_rn(dz, dz));
            INS11(lst, sq);
        }
    }
    WAVEPOP11(lst, s_top[w]);
    __syncthreads();
    if (w == 0) {            // merge 4x11 = 44 -> 11th smallest = T
        const float* flat = &s_top[0][0];
        float a = (lane < 44) ? flat[lane] : FLT_MAX;
        for (int r = 0; r < 11; ++r) {
            float v = a;
#pragma unroll
            for (int off = 32; off >= 1; off >>= 1) v = fminf(v, __shfl_xor(v, off));
            unsigned long long m = __ballot(a == v);
            if (lane == (int)__ffsll(m) - 1) a = FLT_MAX;
            if (r == 10 && lane == 0) s_T = v;
        }
    }
    __syncthreads();
    const float T = s_T;

    // ---- phase 2: hot loop — dist + compare + rare LDS push ----------------
    for (int i = 0; i < 16; ++i) {
        const int pb = c * 16384 + i * 1024 + t * 4;
        const float4* q4 = reinterpret_cast<const float4*>(base + (size_t)pb * 3);
        float4 A = q4[0], Bv = q4[1], Cv = q4[2];
        float px[4] = { A.x, A.w, Bv.z, Cv.y };
        float py[4] = { A.y, Bv.x, Bv.w, Cv.z };
        float pz[4] = { A.z, Bv.y, Cv.x, Cv.w };
#pragma unroll
        for (int q = 0; q < 4; ++q) {
            float dx = __fsub_rn(px[q], cx);
            float dy = __fsub_rn(py[q], cy);
            float dz = __fsub_rn(pz[q], cz);
            float sq = __fadd_rn(__fadd_rn(__fmul_rn(dx, dx), __fmul_rn(dy, dy)),
                                 __fmul_rn(dz, dz));
            if (sq <= T) {
                int idx = atomicAdd(&s_cnt, 1);
                if (idx < CANDCAP) cand[idx] = sq;
            }
        }
    }
    __syncthreads();
    const int n = (s_cnt < CANDCAP) ? s_cnt : CANDCAP;

    // ---- phase 3: exact top-11 of candidates -------------------------------
#pragma unroll
    for (int jj = 0; jj < 11; ++jj) lst[jj] = FLT_MAX;
    for (int idx = t; idx < n; idx += 256) INS11(lst, cand[idx]);
    WAVEPOP11(lst, s_top[w]);
    __syncthreads();
    if (w == 0) {            // merge 44 -> chunk's exact top-11 -> part
        const float* flat = &s_top[0][0];
        float a = (lane < 44) ? flat[lane] : FLT_MAX;
        float* pr = part + (size_t)((b * NS + s) * 4 + c) * 11;
        for (int r = 0; r < 11; ++r) {
            float v = a;
#pragma unroll
            for (int off = 32; off >= 1; off >>= 1) v = fminf(v, __shfl_xor(v, off));
            unsigned long long m = __ballot(a == v);
            if (lane == (int)__ffsll(m) - 1) a = FLT_MAX;
            if (lane == 0) pr[r] = v;
        }
    }
}

// ---------------- Kernel 3: merge 44 -> top-11 + repulsion epilogue ---------
__global__ __launch_bounds__(64) void knn_merge(const float* __restrict__ part,
                                               float* __restrict__ out) {
    const int pair = blockIdx.x;       // 0..319
    const int lane = threadIdx.x;      // 0..63
    const float* flat = part + (size_t)pair * 44;
    float a = (lane < 44) ? flat[lane] : FLT_MAX;

    const float HH = (float)(0.01 * 0.01);   // JAX weak-typed scalar H*H
    float acc = 0.0f;
#pragma unroll
    for (int r = 0; r < 11; ++r) {
        float v = a;
#pragma unroll
        for (int off = 32; off >= 1; off >>= 1) v = fminf(v, __shfl_xor(v, off));
        unsigned long long m = __ballot(a == v);
        if (lane == (int)__ffsll(m) - 1) a = FLT_MAX;
        if (lane == 0 && r >= 1) {           // r==0 is self (dist 0)
            float sq = v;
            float d  = (sq == 0.0f) ? 0.0f : __fsqrt_rn(sq);
            float q2 = __fmul_rn(d, d);
            float wt = expf(__fdiv_rn(-q2, HH));
            acc = __fadd_rn(acc, -__fmul_rn(d, wt));
        }
    }
    if (lane == 0) atomicAdd(out, acc * 0.0625f);   // mean over B=16
}

// ---------------- Host: JAX threefry2x32 (partitionable mode) ---------------
static inline uint32_t rotl32(uint32_t x, uint32_t d) { return (x << d) | (x >> (32 - d)); }

static void tf2x32(uint32_t k0, uint32_t k1, uint32_t x0, uint32_t x1,
                   uint32_t& y0, uint32_t& y1) {
    const uint32_t ks[3] = { k0, k1, k0 ^ k1 ^ 0x1BD11BDAu };
    const uint32_t rotA[4] = { 13, 15, 26, 6 };
    const uint32_t rotB[4] = { 17, 29, 16, 24 };
    uint32_t v0 = x0 + ks[0], v1 = x1 + ks[1];
    for (int i = 0; i < 5; ++i) {
        const uint32_t* rot = (i % 2 == 0) ? rotA : rotB;
        for (int j = 0; j < 4; ++j) {
            v0 += v1;
            v1 = rotl32(v1, rot[j]);
            v1 ^= v0;
        }
        v0 += ks[(i + 1) % 3];
        v1 += ks[(i + 2) % 3] + (uint32_t)(i + 1);
    }
    y0 = v0; y1 = v1;
}

extern "C" void kernel_launch(void* const* d_in, const int* in_sizes, int n_in,
                              void* d_out, int out_size, void* d_ws, size_t ws_size,
                              hipStream_t stream) {
    const float* pcs = (const float*)d_in[0];
    float* out = (float*)d_out;

    // ws: [0,1280) seeds (int); [2048,43008) fps keys u64[16*20*16];
    //     [49152, 49152+320*44*4=105472) part f32
    int* seeds               = (int*)d_ws;
    unsigned long long* fkey = (unsigned long long*)((char*)d_ws + 2048);
    float* part              = (float*)((char*)d_ws + 49152);

    // jax.random.key(1) -> threefry key (0,1), partitionable mode:
    //   split foldlike: k2 = threefry((0,1),(0,1)) both words
    //   random_bits: counters (0,i), out = y0 ^ y1; randint span 2^16 -> mask
    uint32_t k2_0, k2_1;
    tf2x32(0u, 1u, 0u, 1u, k2_0, k2_1);
    InitIdx init;
    for (int i = 0; i < NB; ++i) {
        uint32_t y0, y1;
        tf2x32(k2_0, k2_1, 0u, (uint32_t)i, y0, y1);
        init.idx[i] = (int)((y0 ^ y1) & 0xFFFFu);
    }

    hipMemsetAsync(d_ws, 0, 43008, stream);   // seeds + fps keys
    hipMemsetAsync(d_out, 0, sizeof(float), stream);

    hipLaunchKernelGGL(fps_kernel, dim3(NB * FPB), dim3(1024), 0, stream,
                       pcs, seeds, fkey, init);
    hipLaunchKernelGGL(knn_scan, dim3(1280), dim3(256), 0, stream,
                       pcs, seeds, part);
    hipLaunchKernelGGL(knn_merge, dim3(320), dim3(64), 0, stream,
                       part, out);
}

// Round 18
// 77.114 us; speedup vs baseline: 1.4276x; 1.1197x over previous
//
#include <hip/hip_runtime.h>
#include <cstdint>
#include <cfloat>
#include <cmath>

#define NPTS 65536
#define NB 16
#define NS 20
#define KK 10
#define FPB 16      // FPS blocks per batch
#define NSm1 (NS - 1)

struct InitIdx { int idx[NB]; };

static __device__ __forceinline__ unsigned long long
agent_ld(const unsigned long long* p) {
    return __hip_atomic_load(p, __ATOMIC_RELAXED, __HIP_MEMORY_SCOPE_AGENT);
}

// ---- branchless sorted insert into an 11-list (independent med3 ops) -------
#define INS11(L, SQ)                                                     \
    {                                                                    \
        _Pragma("unroll")                                                \
        for (int jj = 10; jj >= 1; --jj)                                 \
            L[jj] = __builtin_amdgcn_fmed3f(L[jj - 1], L[jj], (SQ));     \
        L[0] = fminf(L[0], (SQ));                                        \
    }

// ---- wave-level top-11 pop of a sorted per-lane list; lane0 -> DEST[r] -----
#define WAVEPOP11(L, DEST)                                               \
    for (int r = 0; r < 11; ++r) {                                       \
        float v = L[0];                                                  \
        _Pragma("unroll")                                                \
        for (int off = 32; off >= 1; off >>= 1)                          \
            v = fminf(v, __shfl_xor(v, off));                            \
        unsigned long long m = __ballot(L[0] == v);                      \
        if (lane == (int)__ffsll(m) - 1) {                               \
            _Pragma("unroll")                                            \
            for (int jj = 0; jj < 10; ++jj) L[jj] = L[jj + 1];           \
            L[10] = FLT_MAX;                                             \
        }                                                                \
        if (lane == 0) (DEST)[r] = v;                                    \
    }

// ---------------- Kernel 1: FPS (R12-verbatim loop) + in-kernel kNN ---------
// 256 blocks (16/batch) x 1024 threads. The FPS loop is BIT-IDENTICAL to the
// R12 structure (46.5us, reproduced 4x). After the loop (all 20 seeds known,
// kept in LDS), the block's 16 waves run the kNN selection for its OWN
// 4096-pt slice: wave w handles seeds {w, w+16} (5 tasks/SIMD, balanced),
// scanning the slice from global (L2-hot: the loop just read it). Each lane
// med3-inserts 64 pts into an 11-list; wave-pop-11 -> part[(pair, block)].
// This removes the separate knn_scan kernel and its 251 MB of L3-bandwidth-
// bound re-reads (the knn-path plateau of R12-R17). R7's fusion failed by
// putting selection INSIDE the sync-critical loop; here it's strictly after.
__global__ __launch_bounds__(1024, 4) void fps_kernel(const float* __restrict__ pcs,
                                                      unsigned long long* __restrict__ fkey,
                                                      float* __restrict__ part,
                                                      InitIdx init) {
    const int u   = blockIdx.x;
    const int xcd = u & 7;              // XCD heuristic (perf-only)
    const int k   = u >> 3;             // 0..31
    const int b   = 2 * xcd + (k >> 4); // batch
    const int j   = k & 15;             // block-in-batch
    const int t   = threadIdx.x;
    const int lane = t & 63;
    const int w    = t >> 6;
    const float* __restrict__ base = pcs + (size_t)b * NPTS * 3;
    const int pbase = j * 4096 + t * 4; // 4 contiguous points per thread

    const float4* q4 = reinterpret_cast<const float4*>(base + (size_t)pbase * 3);
    float4 A = q4[0], Bv = q4[1], Cv = q4[2];
    float x[4] = { A.x, A.w, Bv.z, Cv.y };
    float y[4] = { A.y, Bv.x, Bv.w, Cv.z };
    float z[4] = { A.z, Bv.y, Cv.x, Cv.w };
    float dm[4] = { 1e10f, 1e10f, 1e10f, 1e10f };

    __shared__ float s_val[16];
    __shared__ int   s_idx[16];
    __shared__ int   s_far;
    __shared__ int   s_seeds[NS];

    int far = init.idx[b];

    for (int s = 0; s < NS; ++s) {
        if (t == 0) s_seeds[s] = far;                    // seed s BEFORE update
        if (s == NSm1) break;                            // last update unused

        const float* c = base + (size_t)far * 3;         // uniform, cached
        const float cx = c[0], cy = c[1], cz = c[2];

        float bestv = -1.0f;
        int   besti = 0;
#pragma unroll
        for (int q = 0; q < 4; ++q) {
            // match XLA: rounded sub/mul, sequential adds, NO fma contraction
            float dx = __fsub_rn(x[q], cx);
            float dy = __fsub_rn(y[q], cy);
            float dz = __fsub_rn(z[q], cz);
            float d  = __fadd_rn(__fadd_rn(__fmul_rn(dx, dx), __fmul_rn(dy, dy)),
                                 __fmul_rn(dz, dz));
            dm[q] = fminf(dm[q], d);
            // q ascending = index ascending; strict > keeps first occurrence
            if (dm[q] > bestv) { bestv = dm[q]; besti = pbase + q; }
        }
#pragma unroll
        for (int off = 32; off >= 1; off >>= 1) {
            float ov = __shfl_down(bestv, off);
            int   oi = __shfl_down(besti, off);
            if (ov > bestv || (ov == bestv && oi < besti)) { bestv = ov; besti = oi; }
        }
        if (lane == 0) { s_val[w] = bestv; s_idx[w] = besti; }
        __syncthreads();                                 // B1

        if (w == 0) {
            // parallel 16-lane block reduce -> packed key -> publish
            unsigned long long kv = 0ULL;
            if (lane < 16) {
                kv = ((unsigned long long)__float_as_uint(s_val[lane]) << 32) |
                     (unsigned long long)(0xFFFFFFFFu - (unsigned int)s_idx[lane]);
            }
#pragma unroll
            for (int off = 8; off >= 1; off >>= 1) {
                unsigned int lo = (unsigned int)kv, hi = (unsigned int)(kv >> 32);
                unsigned int olo = (unsigned int)__shfl_xor((int)lo, off);
                unsigned int ohi = (unsigned int)__shfl_xor((int)hi, off);
                unsigned long long o = ((unsigned long long)ohi << 32) | olo;
                if (o > kv) kv = o;
            }
            unsigned long long* fp = fkey + (size_t)(b * NS + s) * FPB;
            if (lane == 0)
                __hip_atomic_store(&fp[j], kv, __ATOMIC_RELAXED,
                                   __HIP_MEMORY_SCOPE_AGENT);

            // 3-deep pipelined poll of the 16 slots (lane l watches slot l&15)
            const unsigned long long* sl = fp + (lane & 15);
            unsigned long long p0 = agent_ld(sl);
            unsigned long long p1 = agent_ld(sl);
            unsigned long long p2 = agent_ld(sl);
            unsigned long long v;
            for (;;) {
                if (!__any(p0 == 0ULL)) { v = p0; break; }
                p0 = agent_ld(sl);
                if (!__any(p1 == 0ULL)) { v = p1; break; }
                p1 = agent_ld(sl);
                if (!__any(p2 == 0ULL)) { v = p2; break; }
                p2 = agent_ld(sl);
            }
#pragma unroll
            for (int off = 32; off >= 1; off >>= 1) {
                unsigned int lo = (unsigned int)v, hi = (unsigned int)(v >> 32);
                unsigned int olo = (unsigned int)__shfl_xor((int)lo, off);
                unsigned int ohi = (unsigned int)__shfl_xor((int)hi, off);
                unsigned long long o = ((unsigned long long)ohi << 32) | olo;
                if (o > v) v = o;
            }
            if (lane == 0)
                s_far = (int)(0xFFFFFFFFu - (unsigned int)(v & 0xFFFFFFFFull));
        }
        __syncthreads();                                 // B2
        far = s_far;
    }

    // ---- post-loop: per-wave kNN selection over this block's slice ---------
    __syncthreads();   // s_seeds complete
#pragma unroll
    for (int pass = 0; pass < 2; ++pass) {
        const int s2 = w + pass * 16;
        if (s2 >= NS) break;                 // wave-uniform
        const int sidx = s_seeds[s2];
        const float ccx = base[(size_t)sidx * 3 + 0];
        const float ccy = base[(size_t)sidx * 3 + 1];
        const float ccz = base[(size_t)sidx * 3 + 2];

        float lst[11];
#pragma unroll
        for (int jj = 0; jj < 11; ++jj) lst[jj] = FLT_MAX;

        for (int i = 0; i < 16; ++i) {
            const int pt = j * 4096 + (i * 64 + lane) * 4;  // 4 contiguous pts
            const float4* qq = reinterpret_cast<const float4*>(base + (size_t)pt * 3);
            float4 qa = qq[0], qb = qq[1], qc = qq[2];
            float px[4] = { qa.x, qa.w, qb.z, qc.y };
            float py[4] = { qa.y, qb.x, qb.w, qc.z };
            float pz[4] = { qa.z, qb.y, qc.x, qc.w };
#pragma unroll
            for (int q = 0; q < 4; ++q) {
                float dx = __fsub_rn(px[q], ccx);
                float dy = __fsub_rn(py[q], ccy);
                float dz = __fsub_rn(pz[q], ccz);
                float sq = __fadd_rn(__fadd_rn(__fmul_rn(dx, dx), __fmul_rn(dy, dy)),
                                     __fmul_rn(dz, dz));
                INS11(lst, sq);
            }
        }
        float* pr = part + ((size_t)(b * NS + s2) * FPB + j) * 11;
        WAVEPOP11(lst, pr);
    }
}

// ---------------- Kernel 2: merge 176 -> top-11 + repulsion epilogue --------
// 320 blocks x 1 wave; R12-verbatim final-merge reading part (16 blocks x 11).
__global__ __launch_bounds__(64) void knn_merge(const float* __restrict__ part,
                                               float* __restrict__ out) {
    const int pair = blockIdx.x;       // 0..319
    const int lane = threadIdx.x;      // 0..63
    const float* flat = part + (size_t)pair * 176;
    float a0 = flat[lane];
    float a1 = flat[lane + 64];
    float a2 = (lane + 128 < 176) ? flat[lane + 128] : FLT_MAX;

    const float HH = (float)(0.01 * 0.01);   // JAX weak-typed scalar H*H
    float acc = 0.0f;
#pragma unroll
    for (int r = 0; r < 11; ++r) {
        float mymin = fminf(a0, fminf(a1, a2));
        float v = mymin;
#pragma unroll
        for (int off = 32; off >= 1; off >>= 1) v = fminf(v, __shfl_xor(v, off));
        unsigned long long m = __ballot(mymin == v);
        if (lane == (int)__ffsll(m) - 1) {
            if (a0 == v)      a0 = FLT_MAX;
            else if (a1 == v) a1 = FLT_MAX;
            else              a2 = FLT_MAX;
        }
        if (lane == 0 && r >= 1) {           // r==0 is self (dist 0)
            float sq = v;
            float d  = (sq == 0.0f) ? 0.0f : __fsqrt_rn(sq);
            float q2 = __fmul_rn(d, d);
            float wt = expf(__fdiv_rn(-q2, HH));
            acc = __fadd_rn(acc, -__fmul_rn(d, wt));
        }
    }
    if (lane == 0) atomicAdd(out, acc * 0.0625f);   // mean over B=16
}

// ---------------- Host: JAX threefry2x32 (partitionable mode) ---------------
static inline uint32_t rotl32(uint32_t x, uint32_t d) { return (x << d) | (x >> (32 - d)); }

static void tf2x32(uint32_t k0, uint32_t k1, uint32_t x0, uint32_t x1,
                   uint32_t& y0, uint32_t& y1) {
    const uint32_t ks[3] = { k0, k1, k0 ^ k1 ^ 0x1BD11BDAu };
    const uint32_t rotA[4] = { 13, 15, 26, 6 };
    const uint32_t rotB[4] = { 17, 29, 16, 24 };
    uint32_t v0 = x0 + ks[0], v1 = x1 + ks[1];
    for (int i = 0; i < 5; ++i) {
        const uint32_t* rot = (i % 2 == 0) ? rotA : rotB;
        for (int j = 0; j < 4; ++j) {
            v0 += v1;
            v1 = rotl32(v1, rot[j]);
            v1 ^= v0;
        }
        v0 += ks[(i + 1) % 3];
        v1 += ks[(i + 2) % 3] + (uint32_t)(i + 1);
    }
    y0 = v0; y1 = v1;
}

extern "C" void kernel_launch(void* const* d_in, const int* in_sizes, int n_in,
                              void* d_out, int out_size, void* d_ws, size_t ws_size,
                              hipStream_t stream) {
    const float* pcs = (const float*)d_in[0];
    float* out = (float*)d_out;

    // ws: [2048,43008) fps keys u64[16*20*16];
    //     [49152, 49152+16*20*16*11*4=274432) part f32 (fully overwritten)
    unsigned long long* fkey = (unsigned long long*)((char*)d_ws + 2048);
    float* part              = (float*)((char*)d_ws + 49152);

    // jax.random.key(1) -> threefry key (0,1), partitionable mode:
    //   split foldlike: k2 = threefry((0,1),(0,1)) both words
    //   random_bits: counters (0,i), out = y0 ^ y1; randint span 2^16 -> mask
    uint32_t k2_0, k2_1;
    tf2x32(0u, 1u, 0u, 1u, k2_0, k2_1);
    InitIdx init;
    for (int i = 0; i < NB; ++i) {
        uint32_t y0, y1;
        tf2x32(k2_0, k2_1, 0u, (uint32_t)i, y0, y1);
        init.idx[i] = (int)((y0 ^ y1) & 0xFFFFu);
    }

    hipMemsetAsync((char*)d_ws + 2048, 0, 40960, stream);   // fps key slots
    hipMemsetAsync(d_out, 0, sizeof(float), stream);

    hipLaunchKernelGGL(fps_kernel, dim3(NB * FPB), dim3(1024), 0, stream,
                       pcs, fkey, part, init);
    hipLaunchKernelGGL(knn_merge, dim3(320), dim3(64), 0, stream,
                       part, out);
}

// Round 19
// 73.241 us; speedup vs baseline: 1.5030x; 1.0529x over previous
//
#include <hip/hip_runtime.h>
#include <cstdint>
#include <cfloat>
#include <cmath>

#define NPTS 65536
#define NB 16
#define NS 20
#define KK 10
#define FPB 16      // FPS blocks per batch
#define NSm1 (NS - 1)

struct InitIdx { int idx[NB]; };

static __device__ __forceinline__ unsigned long long
agent_ld(const unsigned long long* p) {
    return __hip_atomic_load(p, __ATOMIC_RELAXED, __HIP_MEMORY_SCOPE_AGENT);
}
static __device__ __forceinline__ unsigned int
agent_ld32(const unsigned int* p) {
    return __hip_atomic_load(p, __ATOMIC_RELAXED, __HIP_MEMORY_SCOPE_AGENT);
}

// ---- branchless sorted insert into an 11-list (independent med3 ops) -------
#define INS11(L, SQ)                                                     \
    {                                                                    \
        _Pragma("unroll")                                                \
        for (int jj = 10; jj >= 1; --jj)                                 \
            L[jj] = __builtin_amdgcn_fmed3f(L[jj - 1], L[jj], (SQ));     \
        L[0] = fminf(L[0], (SQ));                                        \
    }

// ---------------- Kernel: FPS loop (R12-verbatim) + LDS kNN + tail merge ----
// 256 blocks (16/batch) x 1024 threads.
// Loop: bit-identical to R12 (46.5us, reproduced 5x).
// Post-phase: the block's 4096 pts are staged REGISTERS->LDS SoA (48KB,
//   no global re-read), then wave w selects top-11 for seeds {w, w+16} from
//   LDS (fixes R18's 17us global-latency-bound post-phase; model ~8us) and
//   publishes 11 nonzero u32 keys (fbits(sq)+1, order-preserving) per
//   (pair, block) via relaxed agent stores.
// Tail (R6-proven pattern): block j merges seeds {j, j+16}: wave 0 polls the
//   pair's 176 keys (payload-as-flag, no fence), 11-round pop, repulsion
//   epilogue, atomicAdd. No deadlock: 256 blocks co-resident; every part is
//   written unconditionally before any block enters the tail.
__global__ __launch_bounds__(1024, 4) void fps_kernel(const float* __restrict__ pcs,
                                                      unsigned long long* __restrict__ fkey,
                                                      unsigned int* __restrict__ part,
                                                      float* __restrict__ out,
                                                      InitIdx init) {
    const int u   = blockIdx.x;
    const int xcd = u & 7;              // XCD heuristic (perf-only)
    const int k   = u >> 3;             // 0..31
    const int b   = 2 * xcd + (k >> 4); // batch
    const int j   = k & 15;             // block-in-batch
    const int t   = threadIdx.x;
    const int lane = t & 63;
    const int w    = t >> 6;
    const float* __restrict__ base = pcs + (size_t)b * NPTS * 3;
    const int pbase = j * 4096 + t * 4; // 4 contiguous points per thread

    const float4* q4 = reinterpret_cast<const float4*>(base + (size_t)pbase * 3);
    float4 A = q4[0], Bv = q4[1], Cv = q4[2];
    float x[4] = { A.x, A.w, Bv.z, Cv.y };
    float y[4] = { A.y, Bv.x, Bv.w, Cv.z };
    float z[4] = { A.z, Bv.y, Cv.x, Cv.w };
    float dm[4] = { 1e10f, 1e10f, 1e10f, 1e10f };

    __shared__ float s_val[16];
    __shared__ int   s_idx[16];
    __shared__ int   s_far;
    __shared__ int   s_seeds[NS];
    __shared__ float xs[4096];
    __shared__ float ys[4096];
    __shared__ float zs[4096];

    int far = init.idx[b];

    for (int s = 0; s < NS; ++s) {
        if (t == 0) s_seeds[s] = far;                    // seed s BEFORE update
        if (s == NSm1) break;                            // last update unused

        const float* c = base + (size_t)far * 3;         // uniform, cached
        const float cx = c[0], cy = c[1], cz = c[2];

        float bestv = -1.0f;
        int   besti = 0;
#pragma unroll
        for (int q = 0; q < 4; ++q) {
            // match XLA: rounded sub/mul, sequential adds, NO fma contraction
            float dx = __fsub_rn(x[q], cx);
            float dy = __fsub_rn(y[q], cy);
            float dz = __fsub_rn(z[q], cz);
            float d  = __fadd_rn(__fadd_rn(__fmul_rn(dx, dx), __fmul_rn(dy, dy)),
                                 __fmul_rn(dz, dz));
            dm[q] = fminf(dm[q], d);
            // q ascending = index ascending; strict > keeps first occurrence
            if (dm[q] > bestv) { bestv = dm[q]; besti = pbase + q; }
        }
#pragma unroll
        for (int off = 32; off >= 1; off >>= 1) {
            float ov = __shfl_down(bestv, off);
            int   oi = __shfl_down(besti, off);
            if (ov > bestv || (ov == bestv && oi < besti)) { bestv = ov; besti = oi; }
        }
        if (lane == 0) { s_val[w] = bestv; s_idx[w] = besti; }
        __syncthreads();                                 // B1

        if (w == 0) {
            // parallel 16-lane block reduce -> packed key -> publish
            unsigned long long kv = 0ULL;
            if (lane < 16) {
                kv = ((unsigned long long)__float_as_uint(s_val[lane]) << 32) |
                     (unsigned long long)(0xFFFFFFFFu - (unsigned int)s_idx[lane]);
            }
#pragma unroll
            for (int off = 8; off >= 1; off >>= 1) {
                unsigned int lo = (unsigned int)kv, hi = (unsigned int)(kv >> 32);
                unsigned int olo = (unsigned int)__shfl_xor((int)lo, off);
                unsigned int ohi = (unsigned int)__shfl_xor((int)hi, off);
                unsigned long long o = ((unsigned long long)ohi << 32) | olo;
                if (o > kv) kv = o;
            }
            unsigned long long* fp = fkey + (size_t)(b * NS + s) * FPB;
            if (lane == 0)
                __hip_atomic_store(&fp[j], kv, __ATOMIC_RELAXED,
                                   __HIP_MEMORY_SCOPE_AGENT);

            // 3-deep pipelined poll of the 16 slots (lane l watches slot l&15)
            const unsigned long long* sl = fp + (lane & 15);
            unsigned long long p0 = agent_ld(sl);
            unsigned long long p1 = agent_ld(sl);
            unsigned long long p2 = agent_ld(sl);
            unsigned long long v;
            for (;;) {
                if (!__any(p0 == 0ULL)) { v = p0; break; }
                p0 = agent_ld(sl);
                if (!__any(p1 == 0ULL)) { v = p1; break; }
                p1 = agent_ld(sl);
                if (!__any(p2 == 0ULL)) { v = p2; break; }
                p2 = agent_ld(sl);
            }
#pragma unroll
            for (int off = 32; off >= 1; off >>= 1) {
                unsigned int lo = (unsigned int)v, hi = (unsigned int)(v >> 32);
                unsigned int olo = (unsigned int)__shfl_xor((int)lo, off);
                unsigned int ohi = (unsigned int)__shfl_xor((int)hi, off);
                unsigned long long o = ((unsigned long long)ohi << 32) | olo;
                if (o > v) v = o;
            }
            if (lane == 0)
                s_far = (int)(0xFFFFFFFFu - (unsigned int)(v & 0xFFFFFFFFull));
        }
        __syncthreads();                                 // B2
        far = s_far;
    }

    // ---- stage the slice registers -> LDS SoA (no global re-read) ----------
    {
        float4* xv = reinterpret_cast<float4*>(xs);
        float4* yv = reinterpret_cast<float4*>(ys);
        float4* zv = reinterpret_cast<float4*>(zs);
        xv[t] = make_float4(x[0], x[1], x[2], x[3]);
        yv[t] = make_float4(y[0], y[1], y[2], y[3]);
        zv[t] = make_float4(z[0], z[1], z[2], z[3]);
    }
    __syncthreads();   // s_seeds + LDS slice complete

    // ---- post-phase: wave w selects top-11 for seeds {w, w+16} from LDS ----
#pragma unroll
    for (int pass = 0; pass < 2; ++pass) {
        const int s2 = w + pass * 16;
        if (s2 >= NS) break;                 // wave-uniform
        const int sidx = s_seeds[s2];
        const float ccx = base[(size_t)sidx * 3 + 0];
        const float ccy = base[(size_t)sidx * 3 + 1];
        const float ccz = base[(size_t)sidx * 3 + 2];

        float lst[11];
#pragma unroll
        for (int jj = 0; jj < 11; ++jj) lst[jj] = FLT_MAX;

        const float4* xv = reinterpret_cast<const float4*>(xs);
        const float4* yv = reinterpret_cast<const float4*>(ys);
        const float4* zv = reinterpret_cast<const float4*>(zs);
        for (int i = 0; i < 16; ++i) {
            const int p4 = i * 64 + lane;    // float4 index, 0..1023
            float4 qx = xv[p4], qy = yv[p4], qz = zv[p4];
            float px[4] = { qx.x, qx.y, qx.z, qx.w };
            float py[4] = { qy.x, qy.y, qy.z, qy.w };
            float pz[4] = { qz.x, qz.y, qz.z, qz.w };
#pragma unroll
            for (int q = 0; q < 4; ++q) {
                float dx = __fsub_rn(px[q], ccx);
                float dy = __fsub_rn(py[q], ccy);
                float dz = __fsub_rn(pz[q], ccz);
                float sq = __fadd_rn(__fadd_rn(__fmul_rn(dx, dx), __fmul_rn(dy, dy)),
                                     __fmul_rn(dz, dz));
                INS11(lst, sq);
            }
        }
        // wave-pop 11; lane0 publishes nonzero keys (fbits+1, monotone)
        unsigned int* pr = part + ((size_t)(b * NS + s2) * FPB + j) * 11;
        for (int r = 0; r < 11; ++r) {
            float v = lst[0];
#pragma unroll
            for (int off = 32; off >= 1; off >>= 1) v = fminf(v, __shfl_xor(v, off));
            unsigned long long m = __ballot(lst[0] == v);
            if (lane == (int)__ffsll(m) - 1) {
#pragma unroll
                for (int jj = 0; jj < 10; ++jj) lst[jj] = lst[jj + 1];
                lst[10] = FLT_MAX;
            }
            if (lane == 0)
                __hip_atomic_store(&pr[r], __float_as_uint(v) + 1u,
                                   __ATOMIC_RELAXED, __HIP_MEMORY_SCOPE_AGENT);
        }
    }

    // ---- tail: block j merges seeds {j, j+16}: poll 176 keys, top-11, loss -
    for (int s2 = j; s2 < NS; s2 += FPB) {
        if (w == 0) {
            const unsigned int* sl2 = part + (size_t)(b * NS + s2) * FPB * 11;
            unsigned int k0 = 0, k1 = 0, k2 = (lane + 128 < 176) ? 0u : 1u;
            do {
                if (k0 == 0) k0 = agent_ld32(&sl2[lane]);
                if (k1 == 0) k1 = agent_ld32(&sl2[lane + 64]);
                if (k2 == 0) k2 = agent_ld32(&sl2[lane + 128]);
            } while (__any(k0 == 0 || k1 == 0 || k2 == 0));
            float a0 = __uint_as_float(k0 - 1u);
            float a1 = __uint_as_float(k1 - 1u);
            float a2 = (lane + 128 < 176) ? __uint_as_float(k2 - 1u) : FLT_MAX;

            const float HH = (float)(0.01 * 0.01);     // JAX weak-typed H*H
            float acc = 0.0f;
#pragma unroll
            for (int r = 0; r < 11; ++r) {
                float mymin = fminf(a0, fminf(a1, a2));
                float v = mymin;
#pragma unroll
                for (int off = 32; off >= 1; off >>= 1) v = fminf(v, __shfl_xor(v, off));
                unsigned long long m = __ballot(mymin == v);
                if (lane == (int)__ffsll(m) - 1) {
                    if (a0 == v)      a0 = FLT_MAX;
                    else if (a1 == v) a1 = FLT_MAX;
                    else              a2 = FLT_MAX;
                }
                if (lane == 0 && r >= 1) {             // r==0 is self (dist 0)
                    float sq = v;
                    float dd = (sq == 0.0f) ? 0.0f : __fsqrt_rn(sq);
                    float q2 = __fmul_rn(dd, dd);
                    float wt = expf(__fdiv_rn(-q2, HH));
                    acc = __fadd_rn(acc, -__fmul_rn(dd, wt));
                }
            }
            if (lane == 0) atomicAdd(out, acc * 0.0625f);   // mean over B=16
        }
    }
}

// ---------------- Host: JAX threefry2x32 (partitionable mode) ---------------
static inline uint32_t rotl32(uint32_t x, uint32_t d) { return (x << d) | (x >> (32 - d)); }

static void tf2x32(uint32_t k0, uint32_t k1, uint32_t x0, uint32_t x1,
                   uint32_t& y0, uint32_t& y1) {
    const uint32_t ks[3] = { k0, k1, k0 ^ k1 ^ 0x1BD11BDAu };
    const uint32_t rotA[4] = { 13, 15, 26, 6 };
    const uint32_t rotB[4] = { 17, 29, 16, 24 };
    uint32_t v0 = x0 + ks[0], v1 = x1 + ks[1];
    for (int i = 0; i < 5; ++i) {
        const uint32_t* rot = (i % 2 == 0) ? rotA : rotB;
        for (int j = 0; j < 4; ++j) {
            v0 += v1;
            v1 = rotl32(v1, rot[j]);
            v1 ^= v0;
        }
        v0 += ks[(i + 1) % 3];
        v1 += ks[(i + 2) % 3] + (uint32_t)(i + 1);
    }
    y0 = v0; y1 = v1;
}

extern "C" void kernel_launch(void* const* d_in, const int* in_sizes, int n_in,
                              void* d_out, int out_size, void* d_ws, size_t ws_size,
                              hipStream_t stream) {
    const float* pcs = (const float*)d_in[0];
    float* out = (float*)d_out;

    // ws: [2048,43008) fps keys u64[16*20*16];
    //     [49152, 49152+16*20*16*11*4=274432) part keys u32 (poll-on-zero)
    unsigned long long* fkey = (unsigned long long*)((char*)d_ws + 2048);
    unsigned int* part       = (unsigned int*)((char*)d_ws + 49152);

    // jax.random.key(1) -> threefry key (0,1), partitionable mode:
    //   split foldlike: k2 = threefry((0,1),(0,1)) both words
    //   random_bits: counters (0,i), out = y0 ^ y1; randint span 2^16 -> mask
    uint32_t k2_0, k2_1;
    tf2x32(0u, 1u, 0u, 1u, k2_0, k2_1);
    InitIdx init;
    for (int i = 0; i < NB; ++i) {
        uint32_t y0, y1;
        tf2x32(k2_0, k2_1, 0u, (uint32_t)i, y0, y1);
        init.idx[i] = (int)((y0 ^ y1) & 0xFFFFu);
    }

    // zero fkey + part in one call ([2048, 274432)); d_out separately
    hipMemsetAsync((char*)d_ws + 2048, 0, 272384, stream);
    hipMemsetAsync(d_out, 0, sizeof(float), stream);

    hipLaunchKernelGGL(fps_kernel, dim3(NB * FPB), dim3(1024), 0, stream,
                       pcs, fkey, part, out, init);
}